// Round 8
// baseline (153.270 us; speedup 1.0000x reference)
//
#include <hip/hip_runtime.h>
#include <math.h>

#define SEQ 5
#define EMBC 64   // EMB == CLUSTER == 64

typedef float4 f4;

// ---- 16-lane subgroup reductions via DPP row_ror (VALU pipe, no LDS ops) ----
template<int CTRL>
__device__ __forceinline__ float dpp_rot(float v) {
    return __int_as_float(__builtin_amdgcn_update_dpp(
        0, __float_as_int(v), CTRL, 0xF, 0xF, true));
}
__device__ __forceinline__ float sub_sum(float v) {
    v += dpp_rot<0x128>(v);   // row_ror:8
    v += dpp_rot<0x124>(v);   // row_ror:4
    v += dpp_rot<0x122>(v);   // row_ror:2
    v += dpp_rot<0x121>(v);   // row_ror:1
    return v;
}
__device__ __forceinline__ float sub_max(float v) {
    v = fmaxf(v, dpp_rot<0x128>(v));
    v = fmaxf(v, dpp_rot<0x124>(v));
    v = fmaxf(v, dpp_rot<0x122>(v));
    v = fmaxf(v, dpp_rot<0x121>(v));
    return v;
}
__device__ __forceinline__ float wave_max64(float v) {
    #pragma unroll
    for (int o = 32; o > 0; o >>= 1) v = fmaxf(v, __shfl_xor(v, o, 64));
    return v;
}
__device__ __forceinline__ float wave_sum64(float v) {
    #pragma unroll
    for (int o = 32; o > 0; o >>= 1) v += __shfl_xor(v, o, 64);
    return v;
}
__device__ __forceinline__ float dot4(f4 a, f4 b) {
    return fmaf(a.x, b.x, fmaf(a.y, b.y, fmaf(a.z, b.z, a.w * b.w)));
}
__device__ __forceinline__ f4 fma4(f4 a, float s, f4 c) {
    f4 r; r.x = fmaf(a.x, s, c.x); r.y = fmaf(a.y, s, c.y);
          r.z = fmaf(a.z, s, c.z); r.w = fmaf(a.w, s, c.w); return r;
}
__device__ __forceinline__ f4 add4(f4 a, f4 b) {
    f4 r; r.x = a.x + b.x; r.y = a.y + b.y;
          r.z = a.z + b.z; r.w = a.w + b.w; return r;
}
__device__ __forceinline__ f4 shfl_xor4(f4 v, int mask) {
    f4 r; r.x = __shfl_xor(v.x, mask, 64); r.y = __shfl_xor(v.y, mask, 64);
          r.z = __shfl_xor(v.z, mask, 64); r.w = __shfl_xor(v.w, mask, 64);
    return r;
}
// row softmax of a 64-float vector distributed as float4 over a 16-lane subgroup
__device__ __forceinline__ f4 sub_softmax(f4 a, float scale) {
    a.x *= scale; a.y *= scale; a.z *= scale; a.w *= scale;
    const float m = sub_max(fmaxf(fmaxf(a.x, a.y), fmaxf(a.z, a.w)));
    f4 e; e.x = __expf(a.x - m); e.y = __expf(a.y - m);
          e.z = __expf(a.z - m); e.w = __expf(a.w - m);
    const float inv = 1.0f / sub_sum(((e.x + e.y) + (e.z + e.w)));
    e.x *= inv; e.y *= inv; e.z *= inv; e.w *= inv;
    return e;
}

// ---- Kernel A: column-softmax of w_raw*500 (axis=0), stored TRANSPOSED ----
// wT[d*64+c] = softmax_c(w_raw[:,d]*500)[c]
__global__ __launch_bounds__(64) void wprep_kernel(
    const float* __restrict__ w_raw, float* __restrict__ wT)
{
    const int d = blockIdx.x;
    const int c = threadIdx.x;
    float x = w_raw[c * EMBC + d] * 500.0f;
    const float m = wave_max64(x);
    const float e = __expf(x - m);
    const float s = wave_sum64(e);
    wT[d * EMBC + c] = e / s;   // coalesced write
}

// ---- Kernel B: main — 16 b/block, 4 b/wave; d-split v-loop; NO barriers ----
__global__ __launch_bounds__(256, 4) void rumc_main(
    const int* __restrict__ u_idx, const int* __restrict__ X_idx,
    const int* __restrict__ y_idx,
    const float* __restrict__ item_emb, const float* __restrict__ user_emb,
    const float* __restrict__ ae_raw, const float* __restrict__ wT,
    float* __restrict__ out, int B)
{
    __shared__ f4 s_ae[16 * 16];    // softmaxed aey per subgroup-b: g*16 + sl

    const int t    = threadIdx.x;
    const int wave = t >> 6;
    const int lane = t & 63;
    const int sub  = lane >> 4;    // subgroup 0..3
    const int sl   = lane & 15;    // lane within subgroup
    const int g    = wave * 4 + sub;

    int b = blockIdx.x * 16 + g;
    const bool live = (b < B);
    if (!live) b = B - 1;

    // ---- indices ----
    const int yi = y_idx[b];
    const int ui = u_idx[b];
    int xi[SEQ];
    #pragma unroll
    for (int s = 0; s < SEQ; ++s) xi[s] = X_idx[b * SEQ + s];

    const f4* __restrict__ item4 = (const f4*)item_emb;
    const f4* __restrict__ user4 = (const f4*)user_emb;
    const f4* __restrict__ ae4   = (const f4*)ae_raw;
    const f4* __restrict__ wT4   = (const f4*)wT;

    // ---- all row gathers up front: 13 float4 loads, 1 KB/wave each ----
    f4 aey = ae4[yi * 16 + sl];
    f4 ax[SEQ];
    #pragma unroll
    for (int s = 0; s < SEQ; ++s) ax[s] = ae4[xi[s] * 16 + sl];
    f4 ye = item4[yi * 16 + sl];
    f4 xe[SEQ];
    #pragma unroll
    for (int s = 0; s < SEQ; ++s) xe[s] = item4[xi[s] * 16 + sl];
    f4 ue = user4[ui * 16 + sl];

    // padding_idx = 0 -> zero embedding row (ae row 0 is NOT zeroed)
    if (yi == 0) { ye.x = ye.y = ye.z = ye.w = 0.0f; }
    #pragma unroll
    for (int s = 0; s < SEQ; ++s)
        if (xi[s] == 0) { xe[s].x = xe[s].y = xe[s].z = xe[s].w = 0.0f; }

    // ---- aey softmax; publish to the wave's 4 subgroups (same-wave RAW) ----
    aey = sub_softmax(aey, 50.0f);
    s_ae[g * 16 + sl] = aey;

    // ---- v, d-split: subgroup `sub` covers d in [16*sub,16*sub+16) for ALL
    // 4 wave-b's. w fed from global (L1-hot 16 KB, vmem pipe).
    f4 vp[4];
    #pragma unroll
    for (int bb = 0; bb < 4; ++bb) vp[bb].x = vp[bb].y = vp[bb].z = vp[bb].w = 0.0f;

    #pragma unroll
    for (int jc = 0; jc < 4; ++jc) {            // chunk of 4 d's
        const int d0 = 16 * sub + 4 * jc;       // d-range is per-SUB, within [0,64)
        const f4 w0 = wT4[(d0 + 0) * 16 + sl];  // lane sl -> c = 4sl..4sl+3
        const f4 w1 = wT4[(d0 + 1) * 16 + sl];
        const f4 w2 = wT4[(d0 + 2) * 16 + sl];
        const f4 w3 = wT4[(d0 + 3) * 16 + sl];
        #pragma unroll
        for (int bb = 0; bb < 4; ++bb) {
            // aey[b=bb of wave][f4 chunk d0/4 = 4*sub+jc], broadcast in subgroup
            const f4 a = s_ae[(wave * 4 + bb) * 16 + 4 * sub + jc];
            vp[bb] = fma4(w0, a.x, vp[bb]);
            vp[bb] = fma4(w1, a.y, vp[bb]);
            vp[bb] = fma4(w2, a.z, vp[bb]);
            vp[bb] = fma4(w3, a.w, vp[bb]);
        }
    }
    // cross-subgroup combine: sum over lanes differing in bits 4,5
    #pragma unroll
    for (int bb = 0; bb < 4; ++bb) {
        vp[bb] = add4(vp[bb], shfl_xor4(vp[bb], 16));
        vp[bb] = add4(vp[bb], shfl_xor4(vp[bb], 32));
    }
    // select this subgroup's own b
    f4 v = vp[0];
    if (sub == 1) v = vp[1];
    if (sub == 2) v = vp[2];
    if (sub == 3) v = vp[3];

    // ---- per-position scores ----
    float sc[SEQ];
    #pragma unroll
    for (int s = 0; s < SEQ; ++s) {
        const f4 a = sub_softmax(ax[s], 50.0f);
        const float fac = sub_sum(dot4(a, v));      // aeX . (w @ aeY)
        const float dot = sub_sum(dot4(xe[s], ye)); // X_emb . y_emb
        const float tf = 1.0f - (float)(SEQ - 1 - s) * 0.1f;
        sc[s] = dot * __expf(fac) * tf;             // BETA == 1
    }

    // ---- softmax over SEQ (identical within subgroup) ----
    float ms = sc[0];
    #pragma unroll
    for (int s = 1; s < SEQ; ++s) ms = fmaxf(ms, sc[s]);
    float Z = 0.0f;
    #pragma unroll
    for (int s = 0; s < SEQ; ++s) { sc[s] = __expf(sc[s] - ms); Z += sc[s]; }
    const float invZ = 1.0f / Z;

    // ---- p = sum_s z_s*X_emb[s];  out = sigmoid((p*0.2 + u_emb) . y_emb) ----
    f4 p; p.x = p.y = p.z = p.w = 0.0f;
    #pragma unroll
    for (int s = 0; s < SEQ; ++s) p = fma4(xe[s], sc[s] * invZ, p);
    const f4 pu = fma4(p, 0.2f, ue);
    const float fin = sub_sum(dot4(pu, ye));
    if (live && sl == 0)
        out[b] = 1.0f / (1.0f + __expf(-fin));
}

extern "C" void kernel_launch(void* const* d_in, const int* in_sizes, int n_in,
                              void* d_out, int out_size, void* d_ws, size_t ws_size,
                              hipStream_t stream) {
    const int*   u        = (const int*)d_in[0];
    const int*   X        = (const int*)d_in[1];
    const int*   y        = (const int*)d_in[2];
    const float* item_emb = (const float*)d_in[3];
    const float* user_emb = (const float*)d_in[4];
    const float* ae_raw   = (const float*)d_in[5];
    const float* w_raw    = (const float*)d_in[6];
    float*       out      = (float*)d_out;
    float*       wT       = (float*)d_ws;   // 64*64 floats = 16 KB

    const int B = in_sizes[0];
    const int grid = (B + 15) / 16;

    wprep_kernel<<<EMBC, EMBC, 0, stream>>>(w_raw, wT);
    rumc_main<<<grid, 256, 0, stream>>>(u, X, y, item_emb, user_emb,
                                        ae_raw, wT, out, B);
}

// Round 9
// 141.714 us; speedup vs baseline: 1.0815x; 1.0815x over previous
//
#include <hip/hip_runtime.h>
#include <math.h>

#define SEQ 5
#define EMBC 64   // EMB == CLUSTER == 64

typedef float4 f4;

// ---- 16-lane subgroup reductions via DPP row_ror (VALU pipe, no LDS ops) ----
template<int CTRL>
__device__ __forceinline__ float dpp_rot(float v) {
    return __int_as_float(__builtin_amdgcn_update_dpp(
        0, __float_as_int(v), CTRL, 0xF, 0xF, true));
}
__device__ __forceinline__ float sub_sum(float v) {
    v += dpp_rot<0x128>(v);   // row_ror:8
    v += dpp_rot<0x124>(v);   // row_ror:4
    v += dpp_rot<0x122>(v);   // row_ror:2
    v += dpp_rot<0x121>(v);   // row_ror:1
    return v;
}
__device__ __forceinline__ float sub_max(float v) {
    v = fmaxf(v, dpp_rot<0x128>(v));
    v = fmaxf(v, dpp_rot<0x124>(v));
    v = fmaxf(v, dpp_rot<0x122>(v));
    v = fmaxf(v, dpp_rot<0x121>(v));
    return v;
}
__device__ __forceinline__ float wave_max64(float v) {
    #pragma unroll
    for (int o = 32; o > 0; o >>= 1) v = fmaxf(v, __shfl_xor(v, o, 64));
    return v;
}
__device__ __forceinline__ float wave_sum64(float v) {
    #pragma unroll
    for (int o = 32; o > 0; o >>= 1) v += __shfl_xor(v, o, 64);
    return v;
}
__device__ __forceinline__ float dot4(f4 a, f4 b) {
    return fmaf(a.x, b.x, fmaf(a.y, b.y, fmaf(a.z, b.z, a.w * b.w)));
}
__device__ __forceinline__ f4 fma4(f4 a, float s, f4 c) {
    f4 r; r.x = fmaf(a.x, s, c.x); r.y = fmaf(a.y, s, c.y);
          r.z = fmaf(a.z, s, c.z); r.w = fmaf(a.w, s, c.w); return r;
}
// row softmax of a 64-float vector distributed as float4 over a 16-lane subgroup
__device__ __forceinline__ f4 sub_softmax(f4 a, float scale) {
    a.x *= scale; a.y *= scale; a.z *= scale; a.w *= scale;
    const float m = sub_max(fmaxf(fmaxf(a.x, a.y), fmaxf(a.z, a.w)));
    f4 e; e.x = __expf(a.x - m); e.y = __expf(a.y - m);
          e.z = __expf(a.z - m); e.w = __expf(a.w - m);
    const float inv = 1.0f / sub_sum(((e.x + e.y) + (e.z + e.w)));
    e.x *= inv; e.y *= inv; e.z *= inv; e.w *= inv;
    return e;
}

// ---- Kernel A: column-softmax of w_raw*500 (axis=0), stored TRANSPOSED ----
// wT[d*64+c] = softmax_c(w_raw[:,d]*500)[c]
__global__ __launch_bounds__(64) void wprep_kernel(
    const float* __restrict__ w_raw, float* __restrict__ wT)
{
    const int d = blockIdx.x;
    const int c = threadIdx.x;
    float x = w_raw[c * EMBC + d] * 500.0f;
    const float m = wave_max64(x);
    const float e = __expf(x - m);
    const float s = wave_sum64(e);
    wT[d * EMBC + c] = e / s;   // coalesced write
}

// ---- Kernel B: main — 16 b/block; gathers issued BEFORE staging/barrier ----
__global__ __launch_bounds__(256) void rumc_main(
    const int* __restrict__ u_idx, const int* __restrict__ X_idx,
    const int* __restrict__ y_idx,
    const float* __restrict__ item_emb, const float* __restrict__ user_emb,
    const float* __restrict__ ae_raw, const float* __restrict__ wT,
    float* __restrict__ out, int B)
{
    __shared__ f4 s_w[EMBC * 16];   // wT as f4: [d][c4] = d*16 + c4  (16 KB)
    __shared__ f4 s_ae[16 * 16];    // softmaxed aey per subgroup: g*16 + sl

    const int t    = threadIdx.x;
    const int wave = t >> 6;
    const int lane = t & 63;
    const int sub  = lane >> 4;    // subgroup 0..3
    const int sl   = lane & 15;    // lane within subgroup
    const int g    = wave * 4 + sub;

    int b = blockIdx.x * 16 + g;
    const bool live = (b < B);
    if (!live) b = B - 1;

    // ---- 1. indices first (head of the dependent gather chain) ----
    const int yi = y_idx[b];
    const int ui = u_idx[b];
    int xi[SEQ];
    #pragma unroll
    for (int s = 0; s < SEQ; ++s) xi[s] = X_idx[b * SEQ + s];

    const f4* __restrict__ item4 = (const f4*)item_emb;
    const f4* __restrict__ user4 = (const f4*)user_emb;
    const f4* __restrict__ ae4   = (const f4*)ae_raw;

    // ---- 2. staging loads (independent; fill the index-load latency gap) ----
    f4 stg[4];
    #pragma unroll
    for (int i = 0; i < 4; ++i)
        stg[i] = ((const f4*)wT)[t + 256 * i];

    // ---- 3. all row gathers (13 f4 loads, 1 KB/wave each); latency overlaps
    //         the staging writes + aey softmax below, NOT exposed post-barrier
    f4 aey = ae4[yi * 16 + sl];
    f4 ax[SEQ];
    #pragma unroll
    for (int s = 0; s < SEQ; ++s) ax[s] = ae4[xi[s] * 16 + sl];
    f4 ye = item4[yi * 16 + sl];
    f4 xe[SEQ];
    #pragma unroll
    for (int s = 0; s < SEQ; ++s) xe[s] = item4[xi[s] * 16 + sl];
    f4 ue = user4[ui * 16 + sl];

    // ---- 4. stage wT -> LDS ----
    #pragma unroll
    for (int i = 0; i < 4; ++i)
        s_w[t + 256 * i] = stg[i];

    // padding_idx = 0 -> zero embedding row (ae row 0 is NOT zeroed)
    if (yi == 0) { ye.x = ye.y = ye.z = ye.w = 0.0f; }
    #pragma unroll
    for (int s = 0; s < SEQ; ++s)
        if (xi[s] == 0) { xe[s].x = xe[s].y = xe[s].z = xe[s].w = 0.0f; }

    // ---- 5. aey softmax; publish to subgroup-private LDS line (same-wave) ----
    aey = sub_softmax(aey, 50.0f);
    s_ae[g * 16 + sl] = aey;

    // ---- 6. barrier (only protects s_w) ----
    __syncthreads();

    // ---- v[c] = sum_d w[c][d]*aey[d]; lane sl holds c = 4sl..4sl+3 ----
    f4 v; v.x = v.y = v.z = v.w = 0.0f;
    #pragma unroll
    for (int dd = 0; dd < 16; ++dd) {
        const f4 a  = s_ae[g * 16 + dd];            // 16-lane broadcast read
        const f4 w0 = s_w[(4 * dd + 0) * 16 + sl];  // same addr across subgroups
        const f4 w1 = s_w[(4 * dd + 1) * 16 + sl];
        const f4 w2 = s_w[(4 * dd + 2) * 16 + sl];
        const f4 w3 = s_w[(4 * dd + 3) * 16 + sl];
        v = fma4(w0, a.x, v);
        v = fma4(w1, a.y, v);
        v = fma4(w2, a.z, v);
        v = fma4(w3, a.w, v);
    }

    // ---- per-position scores ----
    float sc[SEQ];
    #pragma unroll
    for (int s = 0; s < SEQ; ++s) {
        const f4 a = sub_softmax(ax[s], 50.0f);
        const float fac = sub_sum(dot4(a, v));      // aeX . (w @ aeY)
        const float dot = sub_sum(dot4(xe[s], ye)); // X_emb . y_emb
        const float tf = 1.0f - (float)(SEQ - 1 - s) * 0.1f;
        sc[s] = dot * __expf(fac) * tf;             // BETA == 1
    }

    // ---- softmax over SEQ (identical within subgroup) ----
    float ms = sc[0];
    #pragma unroll
    for (int s = 1; s < SEQ; ++s) ms = fmaxf(ms, sc[s]);
    float Z = 0.0f;
    #pragma unroll
    for (int s = 0; s < SEQ; ++s) { sc[s] = __expf(sc[s] - ms); Z += sc[s]; }
    const float invZ = 1.0f / Z;

    // ---- p = sum_s z_s*X_emb[s];  out = sigmoid((p*0.2 + u_emb) . y_emb) ----
    f4 p; p.x = p.y = p.z = p.w = 0.0f;
    #pragma unroll
    for (int s = 0; s < SEQ; ++s) p = fma4(xe[s], sc[s] * invZ, p);
    const f4 pu = fma4(p, 0.2f, ue);
    const float fin = sub_sum(dot4(pu, ye));
    if (live && sl == 0)
        out[b] = 1.0f / (1.0f + __expf(-fin));
}

extern "C" void kernel_launch(void* const* d_in, const int* in_sizes, int n_in,
                              void* d_out, int out_size, void* d_ws, size_t ws_size,
                              hipStream_t stream) {
    const int*   u        = (const int*)d_in[0];
    const int*   X        = (const int*)d_in[1];
    const int*   y        = (const int*)d_in[2];
    const float* item_emb = (const float*)d_in[3];
    const float* user_emb = (const float*)d_in[4];
    const float* ae_raw   = (const float*)d_in[5];
    const float* w_raw    = (const float*)d_in[6];
    float*       out      = (float*)d_out;
    float*       wT       = (float*)d_ws;   // 64*64 floats = 16 KB

    const int B = in_sizes[0];
    const int grid = (B + 15) / 16;

    wprep_kernel<<<EMBC, EMBC, 0, stream>>>(w_raw, wT);
    rumc_main<<<grid, 256, 0, stream>>>(u, X, y, item_emb, user_emb,
                                        ae_raw, wT, out, B);
}